// Round 4
// baseline (396.340 us; speedup 1.0000x reference)
//
#include <hip/hip_runtime.h>
#include <stdint.h>

#define DIM    2048
#define NE     64
#define NTOK   32768
#define BM     64          // tokens per block
#define NTHR   512         // 8 waves = 2 token-halves x 4 k-quarters
#define KQ     512         // k per quarter (wk)
#define BK     16          // k per staged chunk per quarter
#define NIT    (KQ/BK)     // 32 iterations
#define WPLANE (NE*DIM)
#define S      68          // epilogue LDS row stride
#define WSBUF  24576       // bytes per ws staging buffer (4q x 3p x 64e x 32B)

typedef __attribute__((ext_vector_type(8)))  short  short8;   // 8 bf16 (4 VGPRs)
typedef __attribute__((ext_vector_type(16))) float  f32x16;   // 32x32 MFMA C/D

typedef __attribute__((address_space(3))) void lds_void_t;
typedef __attribute__((address_space(1))) void gbl_void_t;

// async 16B/lane global->LDS; lds dest = uniform base + lane*16
__device__ __forceinline__ void gload_lds16(const void* gptr, void* lptr) {
    __builtin_amdgcn_global_load_lds((gbl_void_t*)(uintptr_t)gptr,
                                     (lds_void_t*)(uint32_t)(uintptr_t)lptr,
                                     16, 0, 0);
}

// D = (e0 >> 16) | (e1 & 0xffff0000)
__device__ __forceinline__ unsigned pack_hi16(unsigned e0, unsigned e1) {
    return __builtin_amdgcn_perm(e1, e0, 0x07060302u);
}

union U4S8 { uint4 u; short8 s; };

// Exact 3-way bf16 truncation split of 8 fp32 (x = hi + mid + lo exactly)
__device__ __forceinline__ void split8(const float4& a, const float4& b,
                                       short8& h, short8& m, short8& l) {
    const float f[8] = {a.x, a.y, a.z, a.w, b.x, b.y, b.z, b.w};
    unsigned hb[8], mb[8], lb[8];
#pragma unroll
    for (int j = 0; j < 8; ++j) {
        const unsigned xb = __float_as_uint(f[j]);
        const unsigned th = xb & 0xffff0000u;
        const float    rh = f[j] - __uint_as_float(th);
        const unsigned rb = __float_as_uint(rh);
        const unsigned tm = rb & 0xffff0000u;
        const float    rm = rh - __uint_as_float(tm);
        hb[j] = th; mb[j] = tm; lb[j] = __float_as_uint(rm);
    }
    U4S8 H, M, L;
    H.u = make_uint4(pack_hi16(hb[0],hb[1]), pack_hi16(hb[2],hb[3]),
                     pack_hi16(hb[4],hb[5]), pack_hi16(hb[6],hb[7]));
    M.u = make_uint4(pack_hi16(mb[0],mb[1]), pack_hi16(mb[2],mb[3]),
                     pack_hi16(mb[4],mb[5]), pack_hi16(mb[6],mb[7]));
    L.u = make_uint4(pack_hi16(lb[0],lb[1]), pack_hi16(lb[2],lb[3]),
                     pack_hi16(lb[4],lb[5]), pack_hi16(lb[6],lb[7]));
    h = H.s; m = M.s; l = L.s;
}

// Pre-kernel: W fp32 [64][2048] -> 3 bf16 planes in d_ws, layout [plane][e][k]
__global__ void router_wsplit(const float* __restrict__ W, unsigned short* __restrict__ W3)
{
    const int i = blockIdx.x * 256 + threadIdx.x;
    const float f = W[i];
    const unsigned xb = __float_as_uint(f);
    const unsigned th = xb & 0xffff0000u;
    const float    rh = f - __uint_as_float(th);
    const unsigned rb = __float_as_uint(rh);
    const unsigned tm = rb & 0xffff0000u;
    const float    rm = rh - __uint_as_float(tm);
    W3[i]            = (unsigned short)(th >> 16);
    W3[WPLANE + i]   = (unsigned short)(tm >> 16);
    W3[2*WPLANE + i] = (unsigned short)(__float_as_uint(rm) >> 16);
}

#define MFMA(A, B, C) __builtin_amdgcn_mfma_f32_32x32x16_bf16(A, B, C, 0, 0, 0)

__global__ __launch_bounds__(NTHR, 4)
void router_main(const float* __restrict__ x, const unsigned short* __restrict__ W3,
                 float* __restrict__ out_idx, float* __restrict__ out_w,
                 float* __restrict__ gusage)
{
    // ws staging: [buf2][q4][p3][e64][seg2], seg=16B(8 bf16); phys seg s holds
    // global seg s ^ (e&1)  (XOR swizzle: row stride 32B == bank-aligned otherwise).
    // Epilogue overlays the same 48 KB.
    __shared__ __align__(16) unsigned char smem[2 * WSBUF];

    const int tid  = threadIdx.x;
    const int w    = tid >> 6;        // 0..7
    const int ln   = tid & 63;
    const int wk   = w & 3;           // k-quarter: k in [wk*512, wk*512+512)
    const int wi   = w >> 2;          // token half: tokens wi*32..+31
    const int tok0 = blockIdx.x * BM;
    const int arow  = ln & 31;        // fragment row (token / expert)
    const int ahalf = ln >> 5;        // k sub-offset: +8*ahalf

    // ---- ws staging assignment: 3 instrs per wave per iter (24 total) ----
    const int ep = ln >> 1, sb = ln & 1;       // lane -> expert-sub, seg
    uint32_t     ws_lb[3];                     // lds byte offset within buffer (wave-uniform)
    const unsigned short* ws_g[3];             // per-lane global base (kt=0)
#pragma unroll
    for (int i = 0; i < 3; ++i) {
        const int j = w*3 + i, q = j/6, rem = j%6, p = rem>>1, eh = rem&1;
        const int e = eh*32 + ep;
        ws_lb[i] = (uint32_t)((q*3 + p) * 2048 + eh*1024);
        ws_g[i]  = W3 + (size_t)p*WPLANE + (size_t)e*DIM + q*KQ + ((sb ^ (ep & 1)) * 8);
    }

    // ---- x fragment source: direct global, register prefetch ----
    const float* xp = x + (size_t)(tok0 + wi*32 + arow) * DIM + wk*KQ + ahalf*8;

    // ---- B fragment LDS offsets (within buffer) ----
    const int bphys = ahalf ^ (arow & 1);      // un-swizzle
    uint32_t b_off[2][3];
#pragma unroll
    for (int nt = 0; nt < 2; ++nt)
#pragma unroll
        for (int p = 0; p < 3; ++p)
            b_off[nt][p] = (uint32_t)((wk*3 + p)*2048 + (nt*32 + arow)*32 + bphys*16);

    f32x16 acc[2];
#pragma unroll
    for (int nt = 0; nt < 2; ++nt)
#pragma unroll
        for (int r = 0; r < 16; ++r) acc[nt][r] = 0.f;

    float4 xa = *(const float4*)(xp);
    float4 xb = *(const float4*)(xp + 4);

#pragma unroll
    for (int i = 0; i < 3; ++i)                // stage iter 0 -> buf 0
        gload_lds16(ws_g[i], smem + ws_lb[i]);
    __syncthreads();

    for (int kt = 0; kt < NIT; ++kt) {
        const int buf = kt & 1;
        if (kt + 1 < NIT) {                    // stage next chunk -> other buffer
            const unsigned char* dst = smem + (1 - buf) * WSBUF;
#pragma unroll
            for (int i = 0; i < 3; ++i)
                gload_lds16(ws_g[i] + (kt + 1) * BK, (void*)(dst + ws_lb[i]));
        }

        short8 ah, am, al;
        split8(xa, xb, ah, am, al);
        if (kt + 1 < NIT) {                    // x register prefetch (no barrier coupling)
            xa = *(const float4*)(xp + (kt + 1) * BK);
            xb = *(const float4*)(xp + (kt + 1) * BK + 4);
        }

        const unsigned char* wb = smem + buf * WSBUF;
#pragma unroll
        for (int nt = 0; nt < 2; ++nt) {
            const short8 bh = *(const short8*)(wb + b_off[nt][0]);
            const short8 bm = *(const short8*)(wb + b_off[nt][1]);
            const short8 bl = *(const short8*)(wb + b_off[nt][2]);
            acc[nt] = MFMA(ah, bh, acc[nt]);
            acc[nt] = MFMA(am, bh, acc[nt]);
            acc[nt] = MFMA(al, bh, acc[nt]);
            acc[nt] = MFMA(ah, bm, acc[nt]);
            acc[nt] = MFMA(am, bm, acc[nt]);
            acc[nt] = MFMA(ah, bl, acc[nt]);
        }
        __syncthreads();                       // drains next-stage vmcnt + guards buffer reuse
    }

    // ---- epilogue: overlay LDS; reduce 4 k-quarters; top-2 + softmax + usage ----
    float* ps  = (float*)smem;                 // [64][S]
    float* mxa = (float*)(smem + 17408);       // [64]
    float* zia = (float*)(smem + 17664);       // [64]
    float* usa = (float*)(smem + 17920);       // [8][64]

    for (int pass = 0; pass < 4; ++pass) {     // sequential k-partial accumulation
        if (wk == pass) {
#pragma unroll
            for (int nt = 0; nt < 2; ++nt)
#pragma unroll
                for (int r = 0; r < 16; ++r) {
                    const int t = wi*32 + (r & 3) + 8*(r >> 2) + 4*ahalf;  // C/D layout (m74/m101)
                    const int e = nt*32 + arow;
                    if (pass == 0) ps[t*S + e]  = acc[nt][r];
                    else           ps[t*S + e] += acc[nt][r];
                }
        }
        __syncthreads();
    }

    if (tid < BM) {
        const int t = tid;
        float v1 = -3.4e38f, v2 = -3.4e38f;
        int   i1 = 0, i2 = 0;
        for (int e = 0; e < NE; ++e) {
            float s = ps[t*S + e];
            if (s > v1)      { v2 = v1; i2 = i1; v1 = s; i1 = e; }  // strict >: lowest index wins ties
            else if (s > v2) { v2 = s;  i2 = e; }
        }
        float z = 0.f;
        for (int e = 0; e < NE; ++e) z += __expf(ps[t*S + e] - v1);
        mxa[t] = v1;
        zia[t] = 1.f / z;

        const int gt = tok0 + t;
        out_idx[gt*2 + 0] = (float)i1;
        out_idx[gt*2 + 1] = (float)i2;
        float e21 = __expf(v2 - v1);
        float w1  = 1.f / (1.f + e21);
        out_w[gt*2 + 0] = w1;
        out_w[gt*2 + 1] = e21 * w1;
    }
    __syncthreads();

    {   // per-expert usage partials: thread (c,e) sums 8 tokens
        const int e = tid & 63;
        const int c = tid >> 6;
        float u = 0.f;
        for (int t = c*8; t < c*8 + 8; ++t)
            u += __expf(ps[t*S + e] - mxa[t]) * zia[t];
        usa[c*64 + e] = u;
    }
    __syncthreads();
    if (tid < NE) {
        float u = 0.f;
#pragma unroll
        for (int c = 0; c < 8; ++c) u += usa[c*64 + tid];
        atomicAdd(&gusage[tid], u);
    }
}

__global__ void router_finalize(const float* __restrict__ gusage, float* __restrict__ out_aux)
{
    const int e = threadIdx.x;                 // 64 threads = 1 wave
    float u = gusage[e] * (1.0f / (float)NTOK);
    float s = u * u;
#pragma unroll
    for (int off = 32; off > 0; off >>= 1)
        s += __shfl_down(s, off, 64);
    if (e == 0) out_aux[0] = (float)NE * s;
}

extern "C" void kernel_launch(void* const* d_in, const int* in_sizes, int n_in,
                              void* d_out, int out_size, void* d_ws, size_t ws_size,
                              hipStream_t stream)
{
    const float* x = (const float*)d_in[0];
    const float* W = (const float*)d_in[1];
    float* out     = (float*)d_out;
    float* out_idx = out;                 // [4,8192,2] as float
    float* out_w   = out + NTOK * 2;      // [4,8192,2]
    float* out_aux = out + NTOK * 4;      // scalar

    unsigned short* W3 = (unsigned short*)d_ws;   // 3 planes x 128K bf16 = 768 KB
    float* gusage = (float*)((char*)d_ws + 3 * WPLANE * sizeof(unsigned short));

    hipMemsetAsync(gusage, 0, NE * sizeof(float), stream);
    hipLaunchKernelGGL(router_wsplit, dim3(WPLANE / 256), dim3(256), 0, stream, W, W3);
    hipLaunchKernelGGL(router_main, dim3(NTOK / BM), dim3(NTHR), 0, stream,
                       x, W3, out_idx, out_w, gusage);
    hipLaunchKernelGGL(router_finalize, dim3(1), dim3(NE), 0, stream, gusage, out_aux);
}

// Round 5
// 384.528 us; speedup vs baseline: 1.0307x; 1.0307x over previous
//
#include <hip/hip_runtime.h>
#include <stdint.h>

#define DIM    2048
#define NE     64
#define NTOK   32768
#define BM     64          // tokens per block
#define NTHR   512         // 8 waves = 2 expert-halves x 4 k16-quarters
#define BK     64          // k per chunk (one LDS A-tile)
#define NIT    (DIM/BK)    // 32
#define WPLANE (NE*DIM)    // 131072 elems per bf16 plane
#define S      68          // epilogue LDS row stride
#define ABUF   24576       // bytes per A buffer: 3 planes x 64 rows x 128 B

typedef __attribute__((ext_vector_type(8)))  short  short8;   // 8 bf16 (4 VGPRs)
typedef __attribute__((ext_vector_type(16))) float  f32x16;   // 32x32 MFMA C/D

union U4S8 { uint4 u; short8 s; };

// D = (e0 >> 16) | (e1 & 0xffff0000)
__device__ __forceinline__ unsigned pack_hi16(unsigned e0, unsigned e1) {
    return __builtin_amdgcn_perm(e1, e0, 0x07060302u);
}

// Exact 3-way bf16 truncation split of 8 fp32 (x = hi + mid + lo exactly)
__device__ __forceinline__ void split8(const float4& a, const float4& b,
                                       short8& h, short8& m, short8& l) {
    const float f[8] = {a.x, a.y, a.z, a.w, b.x, b.y, b.z, b.w};
    unsigned hb[8], mb[8], lb[8];
#pragma unroll
    for (int j = 0; j < 8; ++j) {
        const unsigned xb = __float_as_uint(f[j]);
        const unsigned th = xb & 0xffff0000u;
        const float    rh = f[j] - __uint_as_float(th);
        const unsigned rb = __float_as_uint(rh);
        const unsigned tm = rb & 0xffff0000u;
        const float    rm = rh - __uint_as_float(tm);
        hb[j] = th; mb[j] = tm; lb[j] = __float_as_uint(rm);
    }
    U4S8 H, M, L;
    H.u = make_uint4(pack_hi16(hb[0],hb[1]), pack_hi16(hb[2],hb[3]),
                     pack_hi16(hb[4],hb[5]), pack_hi16(hb[6],hb[7]));
    M.u = make_uint4(pack_hi16(mb[0],mb[1]), pack_hi16(mb[2],mb[3]),
                     pack_hi16(mb[4],mb[5]), pack_hi16(mb[6],mb[7]));
    L.u = make_uint4(pack_hi16(lb[0],lb[1]), pack_hi16(lb[2],lb[3]),
                     pack_hi16(lb[4],lb[5]), pack_hi16(lb[6],lb[7]));
    h = H.s; m = M.s; l = L.s;
}

// Pre-kernel: W fp32 [64][2048] -> 3 bf16 planes, frag-contiguous layout:
// plane p, k16-block kq, expert e, then 16 bf16 of k. A wave's B-frag load
// (32 e x 32 B) is one contiguous 2 KB span -> perfectly coalesced from L2.
__global__ void router_wsplit(const float* __restrict__ W, unsigned short* __restrict__ W3)
{
    const int i = blockIdx.x * 256 + threadIdx.x;   // 131072
    const int e = i >> 11, k = i & 2047;
    const float f = W[i];
    const unsigned xb = __float_as_uint(f);
    const unsigned th = xb & 0xffff0000u;
    const float    rh = f - __uint_as_float(th);
    const unsigned rb = __float_as_uint(rh);
    const unsigned tm = rb & 0xffff0000u;
    const float    rm = rh - __uint_as_float(tm);
    const int dst = (k >> 4) * 1024 + e * 16 + (k & 15);
    W3[dst]            = (unsigned short)(th >> 16);
    W3[WPLANE + dst]   = (unsigned short)(tm >> 16);
    W3[2*WPLANE + dst] = (unsigned short)(__float_as_uint(rm) >> 16);
}

#define MFMA(A, B, C) __builtin_amdgcn_mfma_f32_32x32x16_bf16(A, B, C, 0, 0, 0)

__global__ __launch_bounds__(NTHR, 4)
void router_main(const float* __restrict__ x, const unsigned short* __restrict__ W3,
                 float* __restrict__ out_idx, float* __restrict__ out_w,
                 float* __restrict__ gusage)
{
    // A staging: [buf2][plane3][row64][chunk8 x 16B], chunk phys = q ^ (r&7)
    // (conflict-free per 8-lane phase on write and read). Epilogue overlays buf0.
    __shared__ __align__(16) unsigned char smem[2 * ABUF];

    const int tid  = threadIdx.x;
    const int w    = tid >> 6;
    const int ln   = tid & 63;
    const int wn   = w & 1;        // expert half: e in [wn*32, wn*32+32)
    const int wkk  = w >> 1;       // k16 quarter within BK chunk (0..3)
    const int tok0 = blockIdx.x * BM;
    const int arow = ln & 31;      // fragment row (token / expert)
    const int kh   = ln >> 5;      // k sub-offset: +8*kh

    // ---- x staging: thread covers row r=tid>>3, chunk q=tid&7 (8 floats, 32 B) ----
    const int xr = tid >> 3, xq = tid & 7;
    const float* xp = x + (size_t)(tok0 + xr) * DIM + xq * 8;
    uint32_t aw[3];
#pragma unroll
    for (int p = 0; p < 3; ++p)
        aw[p] = (uint32_t)(p * 8192 + xr * 128 + ((xq ^ (xr & 7)) * 16));

    // ---- B frag pointers (3 planes); per-kt stride 4096 elems ----
    const unsigned short* bp[3];
#pragma unroll
    for (int p = 0; p < 3; ++p)
        bp[p] = W3 + (size_t)p * WPLANE + wkk * 1024 + wn * 512 + arow * 16 + kh * 8;

    // ---- A frag LDS offsets: 2 mt x 3 planes ----
    uint32_t ar[2][3];
#pragma unroll
    for (int mt = 0; mt < 2; ++mt)
#pragma unroll
        for (int p = 0; p < 3; ++p) {
            const int r = mt * 32 + arow;
            const int q = wkk * 2 + kh;
            ar[mt][p] = (uint32_t)(p * 8192 + r * 128 + ((q ^ (r & 7)) * 16));
        }

    f32x16 acc[2];
#pragma unroll
    for (int mt = 0; mt < 2; ++mt)
#pragma unroll
        for (int r = 0; r < 16; ++r) acc[mt][r] = 0.f;

    // ---- preheader: stage kt=0 A, prefetch kt=1 x, load kt=0 B ----
    float4 xa = *(const float4*)(xp);
    float4 xb = *(const float4*)(xp + 4);
    {
        short8 sh, sm, sl;
        split8(xa, xb, sh, sm, sl);
        *(short8*)(smem + aw[0]) = sh;
        *(short8*)(smem + aw[1]) = sm;
        *(short8*)(smem + aw[2]) = sl;
    }
    xa = *(const float4*)(xp + BK);
    xb = *(const float4*)(xp + BK + 4);
    U4S8 b0, b1, b2;
    b0.u = *(const uint4*)(bp[0]);
    b1.u = *(const uint4*)(bp[1]);
    b2.u = *(const uint4*)(bp[2]);
    __syncthreads();

    for (int kt = 0; kt < NIT; ++kt) {
        const uint32_t cb = (uint32_t)(kt & 1) * ABUF;
        const uint32_t nb = (uint32_t)((kt + 1) & 1) * ABUF;

        // B prefetch for kt+1 (L2-resident, contiguous 2 KB/wave) -- issued early
        U4S8 n0, n1, n2;
        if (kt + 1 < NIT) {
            const int off = (kt + 1) * 4096;
            n0.u = *(const uint4*)(bp[0] + off);
            n1.u = *(const uint4*)(bp[1] + off);
            n2.u = *(const uint4*)(bp[2] + off);
        }

        // split x(kt+1) -> write A into next buffer; then prefetch x(kt+2)
        if (kt + 1 < NIT) {
            short8 sh, sm, sl;
            split8(xa, xb, sh, sm, sl);
            *(short8*)(smem + nb + aw[0]) = sh;
            *(short8*)(smem + nb + aw[1]) = sm;
            *(short8*)(smem + nb + aw[2]) = sl;
            if (kt + 2 < NIT) {
                xa = *(const float4*)(xp + (kt + 2) * BK);
                xb = *(const float4*)(xp + (kt + 2) * BK + 4);
            }
        }

        // compute on current buffer: per mt 3 ds_read_b128 + 6 MFMA pass-terms
#pragma unroll
        for (int mt = 0; mt < 2; ++mt) {
            const short8 ah = *(const short8*)(smem + cb + ar[mt][0]);
            const short8 am = *(const short8*)(smem + cb + ar[mt][1]);
            const short8 al = *(const short8*)(smem + cb + ar[mt][2]);
            acc[mt] = MFMA(ah, b0.s, acc[mt]);
            acc[mt] = MFMA(am, b0.s, acc[mt]);
            acc[mt] = MFMA(al, b0.s, acc[mt]);
            acc[mt] = MFMA(ah, b1.s, acc[mt]);
            acc[mt] = MFMA(am, b1.s, acc[mt]);
            acc[mt] = MFMA(ah, b2.s, acc[mt]);
        }
        b0 = n0; b1 = n1; b2 = n2;
        __syncthreads();   // A(kt+1) writes visible; cb safe to overwrite next iter
    }

    // ---- epilogue: overlay LDS; reduce 4 k-quarters; top-2 + softmax + usage ----
    float* ps  = (float*)smem;                 // [64][S]
    float* mxa = (float*)(smem + 17408);       // [64]
    float* zia = (float*)(smem + 17664);       // [64]
    float* usa = (float*)(smem + 17920);       // [8][64]

    for (int pass = 0; pass < 4; ++pass) {
        if (wkk == pass) {
#pragma unroll
            for (int mt = 0; mt < 2; ++mt)
#pragma unroll
                for (int r = 0; r < 16; ++r) {
                    const int t = mt*32 + (r & 3) + 8*(r >> 2) + 4*kh;   // C/D layout (m74/m101)
                    const int e = wn*32 + arow;
                    if (pass == 0) ps[t*S + e]  = acc[mt][r];
                    else           ps[t*S + e] += acc[mt][r];
                }
        }
        __syncthreads();
    }

    if (tid < BM) {
        const int t = tid;
        float v1 = -3.4e38f, v2 = -3.4e38f;
        int   i1 = 0, i2 = 0;
        for (int e = 0; e < NE; ++e) {
            float s = ps[t*S + e];
            if (s > v1)      { v2 = v1; i2 = i1; v1 = s; i1 = e; }  // strict >: lowest index wins ties
            else if (s > v2) { v2 = s;  i2 = e; }
        }
        float z = 0.f;
        for (int e = 0; e < NE; ++e) z += __expf(ps[t*S + e] - v1);
        mxa[t] = v1;
        zia[t] = 1.f / z;

        const int gt = tok0 + t;
        out_idx[gt*2 + 0] = (float)i1;
        out_idx[gt*2 + 1] = (float)i2;
        float e21 = __expf(v2 - v1);
        float w1  = 1.f / (1.f + e21);
        out_w[gt*2 + 0] = w1;
        out_w[gt*2 + 1] = e21 * w1;
    }
    __syncthreads();

    {   // per-expert usage partials: thread (c,e) sums 8 tokens
        const int e = tid & 63;
        const int c = tid >> 6;
        float u = 0.f;
        for (int t = c*8; t < c*8 + 8; ++t)
            u += __expf(ps[t*S + e] - mxa[t]) * zia[t];
        usa[c*64 + e] = u;
    }
    __syncthreads();
    if (tid < NE) {
        float u = 0.f;
#pragma unroll
        for (int c = 0; c < 8; ++c) u += usa[c*64 + tid];
        atomicAdd(&gusage[tid], u);
    }
}

__global__ void router_finalize(const float* __restrict__ gusage, float* __restrict__ out_aux)
{
    const int e = threadIdx.x;                 // 64 threads = 1 wave
    float u = gusage[e] * (1.0f / (float)NTOK);
    float s = u * u;
#pragma unroll
    for (int off = 32; off > 0; off >>= 1)
        s += __shfl_down(s, off, 64);
    if (e == 0) out_aux[0] = (float)NE * s;
}

extern "C" void kernel_launch(void* const* d_in, const int* in_sizes, int n_in,
                              void* d_out, int out_size, void* d_ws, size_t ws_size,
                              hipStream_t stream)
{
    const float* x = (const float*)d_in[0];
    const float* W = (const float*)d_in[1];
    float* out     = (float*)d_out;
    float* out_idx = out;                 // [4,8192,2] as float
    float* out_w   = out + NTOK * 2;      // [4,8192,2]
    float* out_aux = out + NTOK * 4;      // scalar

    unsigned short* W3 = (unsigned short*)d_ws;   // 3 planes x 128K bf16 = 768 KB
    float* gusage = (float*)((char*)d_ws + 3 * WPLANE * sizeof(unsigned short));

    hipMemsetAsync(gusage, 0, NE * sizeof(float), stream);
    hipLaunchKernelGGL(router_wsplit, dim3(WPLANE / 256), dim3(256), 0, stream, W, W3);
    hipLaunchKernelGGL(router_main, dim3(NTOK / BM), dim3(NTHR), 0, stream,
                       x, W3, out_idx, out_w, gusage);
    hipLaunchKernelGGL(router_finalize, dim3(1), dim3(NE), 0, stream, gusage, out_aux);
}

// Round 6
// 377.897 us; speedup vs baseline: 1.0488x; 1.0175x over previous
//
#include <hip/hip_runtime.h>
#include <stdint.h>

#define DIM    2048
#define NE     64
#define NTOK   32768
#define BM     64          // tokens per block
#define NTHR   512         // 8 waves = 2 expert-halves x 4 k16-quarters
#define BK     64          // k per chunk (one LDS A-tile)
#define NIT    (DIM/BK)    // 32
#define WPLANE (NE*DIM)    // 131072 elems per bf16 plane
#define S      68          // epilogue LDS row stride
#define ABUF   24576       // bytes per A buffer: 64 rows x 3 planes x 128 B

typedef __attribute__((ext_vector_type(8)))  short  short8;   // 8 bf16 (4 VGPRs)
typedef __attribute__((ext_vector_type(16))) float  f32x16;   // 32x32 MFMA C/D

union U4S8 { uint4 u; short8 s; };

// D = (e0 >> 16) | (e1 & 0xffff0000)
__device__ __forceinline__ unsigned pack_hi16(unsigned e0, unsigned e1) {
    return __builtin_amdgcn_perm(e1, e0, 0x07060302u);
}

// Exact 3-way bf16 truncation split of 8 fp32 (x = hi + mid + lo exactly)
__device__ __forceinline__ void split8(const float4& a, const float4& b,
                                       short8& h, short8& m, short8& l) {
    const float f[8] = {a.x, a.y, a.z, a.w, b.x, b.y, b.z, b.w};
    unsigned hb[8], mb[8], lb[8];
#pragma unroll
    for (int j = 0; j < 8; ++j) {
        const unsigned xb = __float_as_uint(f[j]);
        const unsigned th = xb & 0xffff0000u;
        const float    rh = f[j] - __uint_as_float(th);
        const unsigned rb = __float_as_uint(rh);
        const unsigned tm = rb & 0xffff0000u;
        const float    rm = rh - __uint_as_float(tm);
        hb[j] = th; mb[j] = tm; lb[j] = __float_as_uint(rm);
    }
    U4S8 H, M, L;
    H.u = make_uint4(pack_hi16(hb[0],hb[1]), pack_hi16(hb[2],hb[3]),
                     pack_hi16(hb[4],hb[5]), pack_hi16(hb[6],hb[7]));
    M.u = make_uint4(pack_hi16(mb[0],mb[1]), pack_hi16(mb[2],mb[3]),
                     pack_hi16(mb[4],mb[5]), pack_hi16(mb[6],mb[7]));
    L.u = make_uint4(pack_hi16(lb[0],lb[1]), pack_hi16(lb[2],lb[3]),
                     pack_hi16(lb[4],lb[5]), pack_hi16(lb[6],lb[7]));
    h = H.s; m = M.s; l = L.s;
}

// Pre-kernel: W fp32 [64][2048] -> 3 bf16 planes, frag-contiguous layout:
// plane p, k16-block kq, expert e, 16 bf16 of k. A wave's B-frag load is one
// contiguous 2 KB span -> perfectly coalesced from L2. (unchanged from R5)
__global__ void router_wsplit(const float* __restrict__ W, unsigned short* __restrict__ W3)
{
    const int i = blockIdx.x * 256 + threadIdx.x;   // 131072
    const int e = i >> 11, k = i & 2047;
    const float f = W[i];
    const unsigned xb = __float_as_uint(f);
    const unsigned th = xb & 0xffff0000u;
    const float    rh = f - __uint_as_float(th);
    const unsigned rb = __float_as_uint(rh);
    const unsigned tm = rb & 0xffff0000u;
    const float    rm = rh - __uint_as_float(tm);
    const int dst = (k >> 4) * 1024 + e * 16 + (k & 15);
    W3[dst]            = (unsigned short)(th >> 16);
    W3[WPLANE + dst]   = (unsigned short)(tm >> 16);
    W3[2*WPLANE + dst] = (unsigned short)(__float_as_uint(rm) >> 16);
}

#define MFMA(A, B, C) __builtin_amdgcn_mfma_f32_32x32x16_bf16(A, B, C, 0, 0, 0)

__global__ __launch_bounds__(NTHR, 4)
void router_main(const float* __restrict__ x, const unsigned short* __restrict__ W3,
                 float* __restrict__ out_idx, float* __restrict__ out_w,
                 float* __restrict__ gusage)
{
    // A buffer phys layout: byte = row*384 + plane*128 + ((q ^ (row&7))*16),
    // q = 16B chunk 0..7. Row stride 384B (dword 96 = 0 mod 32) + XOR swizzle:
    // max 2-way per 16-lane phase on write and read (free, m136).
    // Single addr VGPR each side; plane/mt/buffer are immediate ds offsets.
    __shared__ __align__(16) unsigned char smem[2 * ABUF];

    const int tid  = threadIdx.x;
    const int w    = tid >> 6;
    const int ln   = tid & 63;
    const int wn   = w & 1;        // expert half
    const int wkk  = w >> 1;       // k16 quarter within BK chunk (0..3)
    const int tok0 = blockIdx.x * BM;
    const int arow = ln & 31;      // fragment row (token / expert)
    const int kh   = ln >> 5;      // k sub-offset: +8*kh

    // ---- x staging: thread covers row xr=tid>>3, chunk xq=tid&7 (32 B) ----
    const int xr = tid >> 3, xq = tid & 7;
    const float* xp = x + (size_t)(tok0 + xr) * DIM + xq * 8;
    const uint32_t awb = (uint32_t)(xr * 384 + ((xq ^ (xr & 7)) * 16));

    // ---- B frag: one base + 3 voffsets (bytes), stride 8192 B per kt ----
    const uint32_t bvo = (uint32_t)((wkk * 1024 + wn * 512 + arow * 16 + kh * 8) * 2);

    // ---- A frag read base (mt/plane/buf via immediates) ----
    const int aq = wkk * 2 + kh;
    const uint32_t arb = (uint32_t)(arow * 384 + ((aq ^ (arow & 7)) * 16));

    f32x16 acc[2];
#pragma unroll
    for (int mt = 0; mt < 2; ++mt)
#pragma unroll
        for (int r = 0; r < 16; ++r) acc[mt][r] = 0.f;

    // ---- preheader: stage kt=0 A, prefetch kt=1 x, load kt=0 B ----
    float4 xa = *(const float4*)(xp);
    float4 xb = *(const float4*)(xp + 4);
    {
        short8 sh, sm, sl;
        split8(xa, xb, sh, sm, sl);
        *(short8*)(smem + awb)       = sh;
        *(short8*)(smem + awb + 128) = sm;
        *(short8*)(smem + awb + 256) = sl;
    }
    xa = *(const float4*)(xp + BK);
    xb = *(const float4*)(xp + BK + 4);
    U4S8 b0, b1, b2;
    b0.u = *(const uint4*)((const unsigned char*)W3 + bvo);
    b1.u = *(const uint4*)((const unsigned char*)W3 + bvo + 2*WPLANE);
    b2.u = *(const uint4*)((const unsigned char*)W3 + bvo + 4*WPLANE);
    __syncthreads();

#pragma unroll 2
    for (int kt = 0; kt < NIT; ++kt) {
        const uint32_t cb = (uint32_t)(kt & 1) * ABUF;
        const uint32_t nb = ABUF - cb;

        // B prefetch for kt+1 (L2-resident, contiguous 2 KB/wave)
        U4S8 n0, n1, n2;
        if (kt + 1 < NIT) {
            const uint32_t off = bvo + (uint32_t)(kt + 1) * 8192;
            n0.u = *(const uint4*)((const unsigned char*)W3 + off);
            n1.u = *(const uint4*)((const unsigned char*)W3 + off + 2*WPLANE);
            n2.u = *(const uint4*)((const unsigned char*)W3 + off + 4*WPLANE);
        }

        // split x(kt+1) -> next buffer; prefetch x(kt+2)
        if (kt + 1 < NIT) {
            short8 sh, sm, sl;
            split8(xa, xb, sh, sm, sl);
            *(short8*)(smem + nb + awb)       = sh;
            *(short8*)(smem + nb + awb + 128) = sm;
            *(short8*)(smem + nb + awb + 256) = sl;
            if (kt + 2 < NIT) {
                xa = *(const float4*)(xp + (kt + 2) * BK);
                xb = *(const float4*)(xp + (kt + 2) * BK + 4);
            }
        }

        // compute on current buffer: 3 ds_read_b128 + 6 MFMA per mt
#pragma unroll
        for (int mt = 0; mt < 2; ++mt) {
            const unsigned char* base = smem + cb + arb + mt * 12288;
            const short8 ah = *(const short8*)(base);
            const short8 am = *(const short8*)(base + 128);
            const short8 al = *(const short8*)(base + 256);
            acc[mt] = MFMA(ah, b0.s, acc[mt]);
            acc[mt] = MFMA(am, b0.s, acc[mt]);
            acc[mt] = MFMA(al, b0.s, acc[mt]);
            acc[mt] = MFMA(ah, b1.s, acc[mt]);
            acc[mt] = MFMA(am, b1.s, acc[mt]);
            acc[mt] = MFMA(ah, b2.s, acc[mt]);
        }
        b0 = n0; b1 = n1; b2 = n2;
        __syncthreads();   // A(kt+1) writes visible; cb reusable next iter
    }

    // ---- epilogue: overlay LDS; reduce 4 k-quarters; top-2 + softmax + usage ----
    float* ps  = (float*)smem;                 // [64][S]
    float* mxa = (float*)(smem + 17408);       // [64]
    float* zia = (float*)(smem + 17664);       // [64]
    float* usa = (float*)(smem + 17920);       // [8][64]

    for (int pass = 0; pass < 4; ++pass) {
        if (wkk == pass) {
#pragma unroll
            for (int mt = 0; mt < 2; ++mt)
#pragma unroll
                for (int r = 0; r < 16; ++r) {
                    const int t = mt*32 + (r & 3) + 8*(r >> 2) + 4*kh;   // C/D layout (m74/m101)
                    const int e = wn*32 + arow;
                    if (pass == 0) ps[t*S + e]  = acc[mt][r];
                    else           ps[t*S + e] += acc[mt][r];
                }
        }
        __syncthreads();
    }

    if (tid < BM) {
        const int t = tid;
        float v1 = -3.4e38f, v2 = -3.4e38f;
        int   i1 = 0, i2 = 0;
        for (int e = 0; e < NE; ++e) {
            float s = ps[t*S + e];
            if (s > v1)      { v2 = v1; i2 = i1; v1 = s; i1 = e; }  // strict >: lowest index wins ties
            else if (s > v2) { v2 = s;  i2 = e; }
        }
        float z = 0.f;
        for (int e = 0; e < NE; ++e) z += __expf(ps[t*S + e] - v1);
        mxa[t] = v1;
        zia[t] = 1.f / z;

        const int gt = tok0 + t;
        out_idx[gt*2 + 0] = (float)i1;
        out_idx[gt*2 + 1] = (float)i2;
        float e21 = __expf(v2 - v1);
        float w1  = 1.f / (1.f + e21);
        out_w[gt*2 + 0] = w1;
        out_w[gt*2 + 1] = e21 * w1;
    }
    __syncthreads();

    {   // per-expert usage partials: thread (c,e) sums 8 tokens
        const int e = tid & 63;
        const int c = tid >> 6;
        float u = 0.f;
        for (int t = c*8; t < c*8 + 8; ++t)
            u += __expf(ps[t*S + e] - mxa[t]) * zia[t];
        usa[c*64 + e] = u;
    }
    __syncthreads();
    if (tid < NE) {
        float u = 0.f;
#pragma unroll
        for (int c = 0; c < 8; ++c) u += usa[c*64 + tid];
        atomicAdd(&gusage[tid], u);
    }
}

__global__ void router_finalize(const float* __restrict__ gusage, float* __restrict__ out_aux)
{
    const int e = threadIdx.x;                 // 64 threads = 1 wave
    float u = gusage[e] * (1.0f / (float)NTOK);
    float s = u * u;
#pragma unroll
    for (int off = 32; off > 0; off >>= 1)
        s += __shfl_down(s, off, 64);
    if (e == 0) out_aux[0] = (float)NE * s;
}

extern "C" void kernel_launch(void* const* d_in, const int* in_sizes, int n_in,
                              void* d_out, int out_size, void* d_ws, size_t ws_size,
                              hipStream_t stream)
{
    const float* x = (const float*)d_in[0];
    const float* W = (const float*)d_in[1];
    float* out     = (float*)d_out;
    float* out_idx = out;                 // [4,8192,2] as float
    float* out_w   = out + NTOK * 2;      // [4,8192,2]
    float* out_aux = out + NTOK * 4;      // scalar

    unsigned short* W3 = (unsigned short*)d_ws;   // 3 planes x 128K bf16 = 768 KB
    float* gusage = (float*)((char*)d_ws + 3 * WPLANE * sizeof(unsigned short));

    hipMemsetAsync(gusage, 0, NE * sizeof(float), stream);
    hipLaunchKernelGGL(router_wsplit, dim3(WPLANE / 256), dim3(256), 0, stream, W, W3);
    hipLaunchKernelGGL(router_main, dim3(NTOK / BM), dim3(NTHR), 0, stream,
                       x, W3, out_idx, out_w, gusage);
    hipLaunchKernelGGL(router_finalize, dim3(1), dim3(NE), 0, stream, gusage, out_aux);
}